// Round 15
// baseline (508.723 us; speedup 1.0000x reference)
//
#include <hip/hip_runtime.h>
#include <math.h>

#define NT 256    // small kernels
#define NTS 512   // sage_layer: 8 waves, WL+WR in 32KB LDS, 4 blocks/CU

__device__ __forceinline__ float rlf(float v, int l) {
    return __int_as_float(__builtin_amdgcn_readlane(__float_as_int(v), l));
}
__device__ __forceinline__ int rli(int v, int l) {
    return __builtin_amdgcn_readlane(v, l);
}
__device__ __forceinline__ int imin(int a, int b) { return a < b ? a : b; }
__device__ __forceinline__ int imax(int a, int b) { return a > b ? a : b; }

// ---------------- CSR build ----------------

__global__ void zero_i32(int* __restrict__ p, int n) {
    int t = blockIdx.x * blockDim.x + threadIdx.x;
    if (t < n) p[t] = 0;
}

__global__ void hist_dst(int* __restrict__ cnt, const int* __restrict__ dst, int n_edges) {
    int e = blockIdx.x * blockDim.x + threadIdx.x;
    if (e < n_edges) atomicAdd(&cnt[dst[e]], 1);
}

// ---- parallel 3-kernel exclusive scan of cnt[0..n) ----
__global__ void scan_blocks(const int* __restrict__ cnt, int* __restrict__ bsum, int n) {
    __shared__ int s[NT];
    int i = blockIdx.x * NT + threadIdx.x;
    s[threadIdx.x] = (i < n) ? cnt[i] : 0;
    __syncthreads();
    for (int off = NT / 2; off > 0; off >>= 1) {
        if (threadIdx.x < off) s[threadIdx.x] += s[threadIdx.x + off];
        __syncthreads();
    }
    if (threadIdx.x == 0) bsum[blockIdx.x] = s[0];
}

__global__ void scan_bsum(const int* __restrict__ bsum, int* __restrict__ boff,
                          int nb, int* __restrict__ row_off, int n) {
    __shared__ int s[1024];
    int tid = threadIdx.x;
    int v = (tid < nb) ? bsum[tid] : 0;
    s[tid] = v;
    __syncthreads();
    for (int off = 1; off < 1024; off <<= 1) {
        int t = (tid >= off) ? s[tid - off] : 0;
        __syncthreads();
        s[tid] += t;
        __syncthreads();
    }
    if (tid < nb) boff[tid] = s[tid] - v;
    if (tid == nb - 1) row_off[n] = s[tid];
}

__global__ void scan_final(const int* __restrict__ cnt, const int* __restrict__ boff,
                           int* __restrict__ row_off, int* __restrict__ cursor, int n) {
    __shared__ int s[NT];
    int i = blockIdx.x * NT + threadIdx.x;
    int v = (i < n) ? cnt[i] : 0;
    s[threadIdx.x] = v;
    __syncthreads();
    for (int off = 1; off < NT; off <<= 1) {
        int t = (threadIdx.x >= off) ? s[threadIdx.x - off] : 0;
        __syncthreads();
        s[threadIdx.x] += t;
        __syncthreads();
    }
    if (i < n) {
        int ex = boff[blockIdx.x] + s[threadIdx.x] - v;
        row_off[i] = ex;
        cursor[i] = ex;
    }
}

__global__ void edge_scatter(int* __restrict__ csr_src, int* __restrict__ cursor,
                             const int* __restrict__ src, const int* __restrict__ dst,
                             int n_edges) {
    int e = blockIdx.x * blockDim.x + threadIdx.x;
    if (e < n_edges) {
        int p = atomicAdd(&cursor[dst[e]], 1);
        csr_src[p] = src[e];
    }
}

// ---------------- pooling helpers ----------------

__global__ void pool_init(float* __restrict__ pooled, int n) {
    int t = blockIdx.x * blockDim.x + threadIdx.x;
    if (t < n) pooled[t] = -INFINITY;
}

__device__ __forceinline__ void atomicMaxFloat(float* addr, float value) {
    if (value >= 0.0f)
        atomicMax((int*)addr, __float_as_int(value));
    else
        atomicMin((unsigned int*)addr, (unsigned int)__float_as_int(value));
}

// ---------------- fused SAGE layer ----------------
// r13 structure with PAIR-INTERLEAVED gather: nodes (0,1) and (2,3) issue
// their 8-load groups back-to-back -> 16 loads in flight per wave (vs 8).
// Guards are wave-uniform SALU; no per-lane clamps added. Everything else
// (LDS weights, dense phase, scan, scatter, head) identical to r13.
__global__ __launch_bounds__(NTS, 4) void sage_layer(
    float* __restrict__ out, float* __restrict__ pooled,
    const float* __restrict__ h_in,
    const int* __restrict__ row_off, const int* __restrict__ csr_src,
    const int* __restrict__ batch,
    const float* __restrict__ Wl, const float* __restrict__ Wr,
    const float* __restrict__ bl,
    int n_nodes, int do_pool) {
    __shared__ float WL[4096];  // WL[k4*256 + f*4 + kk] = Wl[f][k4*4+kk]
    __shared__ float WR[4096];
    int tid = threadIdx.x;
    for (int t = tid; t < 4096; t += NTS) {
        int kk = t & 3, f = (t >> 2) & 63, k4 = t >> 8;
        WL[t] = Wl[f * 64 + k4 * 4 + kk];
        WR[t] = Wr[f * 64 + k4 * 4 + kk];
    }
    __syncthreads();

    int lane = tid & 63;
    int gwave = (blockIdx.x * NTS + tid) >> 6;
    int nwaves = (gridDim.x * NTS) >> 6;
    float bias = bl[lane];

    for (int q = gwave; q * 4 < n_nodes; q += nwaves) {
        int base = q * 4;
        bool quad_ok = (base + 4 <= n_nodes);

        float mean0 = 0.f, mean1 = 0.f, mean2 = 0.f, mean3 = 0.f;
        float hv0 = 0.f, hv1 = 0.f, hv2 = 0.f, hv3 = 0.f;

        int b0 = 0, b1 = 0, b2 = 0, b3 = 0;
        int d0 = 0, d1 = 0, d2 = 0, d3 = 0, dmax = 0;
        if (quad_ok) {
            int ro = row_off[base + (lane < 4 ? lane : 4)];
            b0 = rli(ro, 0); b1 = rli(ro, 1); b2 = rli(ro, 2); b3 = rli(ro, 3);
            int e3 = rli(ro, 4);
            d0 = b1 - b0; d1 = b2 - b1; d2 = b3 - b2; d3 = e3 - b3;
            dmax = imax(imax(d0, d1), imax(d2, d3));
        }

        if (quad_ok && dmax <= 64) {
            // hoisted independent loads: 4 idx vectors + 4 hv rows
            int idx0 = csr_src[b0 + (lane < d0 ? lane : imax(d0 - 1, 0))];
            int idx1 = csr_src[b1 + (lane < d1 ? lane : imax(d1 - 1, 0))];
            int idx2 = csr_src[b2 + (lane < d2 ? lane : imax(d2 - 1, 0))];
            int idx3 = csr_src[b3 + (lane < d3 ? lane : imax(d3 - 1, 0))];
            hv0 = h_in[((base + 0) << 6) + lane];
            hv1 = h_in[((base + 1) << 6) + lane];
            hv2 = h_in[((base + 2) << 6) + lane];
            hv3 = h_in[((base + 3) << 6) + lane];

// pair-interleaved gather: issue A group, issue B group (16 in flight),
// then consume A, consume B.
#define PAIR_GATHER(MEANA, MEANB, IDXA, IDXB, DA, DB)                         \
            {                                                                 \
                int mA = (DA), mB = (DB);                                     \
                int gmax = imax(mA, mB);                                      \
                float aA0 = 0.f, aA1 = 0.f, aB0 = 0.f, aB1 = 0.f;             \
                for (int j = 0; j < gmax; j += 8) {                           \
                    float vA0, vA1, vA2, vA3, vA4, vA5, vA6, vA7;             \
                    float vB0, vB1, vB2, vB3, vB4, vB5, vB6, vB7;             \
                    bool doA = j < mA, doB = j < mB;                          \
                    if (doA) {                                                \
                        int mmA = mA - 1;                                     \
                        vA0 = h_in[(rli(IDXA, j) << 6) + lane];               \
                        vA1 = h_in[(rli(IDXA, j+1 < mA ? j+1 : mmA) << 6) + lane]; \
                        vA2 = h_in[(rli(IDXA, j+2 < mA ? j+2 : mmA) << 6) + lane]; \
                        vA3 = h_in[(rli(IDXA, j+3 < mA ? j+3 : mmA) << 6) + lane]; \
                        vA4 = h_in[(rli(IDXA, j+4 < mA ? j+4 : mmA) << 6) + lane]; \
                        vA5 = h_in[(rli(IDXA, j+5 < mA ? j+5 : mmA) << 6) + lane]; \
                        vA6 = h_in[(rli(IDXA, j+6 < mA ? j+6 : mmA) << 6) + lane]; \
                        vA7 = h_in[(rli(IDXA, j+7 < mA ? j+7 : mmA) << 6) + lane]; \
                    }                                                         \
                    if (doB) {                                                \
                        int mmB = mB - 1;                                     \
                        vB0 = h_in[(rli(IDXB, j) << 6) + lane];               \
                        vB1 = h_in[(rli(IDXB, j+1 < mB ? j+1 : mmB) << 6) + lane]; \
                        vB2 = h_in[(rli(IDXB, j+2 < mB ? j+2 : mmB) << 6) + lane]; \
                        vB3 = h_in[(rli(IDXB, j+3 < mB ? j+3 : mmB) << 6) + lane]; \
                        vB4 = h_in[(rli(IDXB, j+4 < mB ? j+4 : mmB) << 6) + lane]; \
                        vB5 = h_in[(rli(IDXB, j+5 < mB ? j+5 : mmB) << 6) + lane]; \
                        vB6 = h_in[(rli(IDXB, j+6 < mB ? j+6 : mmB) << 6) + lane]; \
                        vB7 = h_in[(rli(IDXB, j+7 < mB ? j+7 : mmB) << 6) + lane]; \
                    }                                                         \
                    if (doA) {                                                \
                        aA0 += vA0;                                           \
                        aA1 += (j + 1 < mA) ? vA1 : 0.f;                      \
                        aA0 += (j + 2 < mA) ? vA2 : 0.f;                      \
                        aA1 += (j + 3 < mA) ? vA3 : 0.f;                      \
                        aA0 += (j + 4 < mA) ? vA4 : 0.f;                      \
                        aA1 += (j + 5 < mA) ? vA5 : 0.f;                      \
                        aA0 += (j + 6 < mA) ? vA6 : 0.f;                      \
                        aA1 += (j + 7 < mA) ? vA7 : 0.f;                      \
                    }                                                         \
                    if (doB) {                                                \
                        aB0 += vB0;                                           \
                        aB1 += (j + 1 < mB) ? vB1 : 0.f;                      \
                        aB0 += (j + 2 < mB) ? vB2 : 0.f;                      \
                        aB1 += (j + 3 < mB) ? vB3 : 0.f;                      \
                        aB0 += (j + 4 < mB) ? vB4 : 0.f;                      \
                        aB1 += (j + 5 < mB) ? vB5 : 0.f;                      \
                        aB0 += (j + 6 < mB) ? vB6 : 0.f;                      \
                        aB1 += (j + 7 < mB) ? vB7 : 0.f;                      \
                    }                                                         \
                }                                                             \
                MEANA = (aA0 + aA1) * (1.0f / (float)imax(mA, 1));            \
                MEANB = (aB0 + aB1) * (1.0f / (float)imax(mB, 1));            \
            }
            PAIR_GATHER(mean0, mean1, idx0, idx1, d0, d1)
            PAIR_GATHER(mean2, mean3, idx2, idx3, d2, d3)
#undef PAIR_GATHER
        } else {
            // ---- generic slow path (tail quad or deg > 64) ----
#define GATHER_NODE(MEAN, HV, N)                                              \
            {                                                                 \
                int i = base + (N);                                           \
                if (i < n_nodes) {                                            \
                    int beg = row_off[i];                                     \
                    int end_ = row_off[i + 1];                                \
                    int deg = end_ - beg;                                     \
                    float aa = 0.f;                                           \
                    for (int cb = beg; cb < end_; cb += 64) {                 \
                        int m = end_ - cb; if (m > 64) m = 64;                \
                        int lidx = cb + (lane < m ? lane : m - 1);            \
                        int idx = csr_src[lidx];                              \
                        for (int j = 0; j < m; ++j)                           \
                            aa += h_in[(rli(idx, j) << 6) + lane];            \
                    }                                                         \
                    MEAN = aa * (1.0f / (float)(deg > 0 ? deg : 1));          \
                    HV = h_in[((size_t)i << 6) + lane];                       \
                }                                                             \
            }
            GATHER_NODE(mean0, hv0, 0)
            GATHER_NODE(mean1, hv1, 1)
            GATHER_NODE(mean2, hv2, 2)
            GATHER_NODE(mean3, hv3, 3)
#undef GATHER_NODE
        }

        float o0 = bias, o1 = bias, o2 = bias, o3 = bias;
        for (int k4 = 0; k4 < 16; ++k4) {
            float4 wl = *(const float4*)&WL[k4 * 256 + lane * 4];
            float4 wr = *(const float4*)&WR[k4 * 256 + lane * 4];
            int kb = k4 * 4;
#define DENSE_KK(WLK, WRK, KK)                                                \
            {                                                                 \
                int k = kb + (KK);                                            \
                o0 += rlf(mean0, k) * (WLK) + rlf(hv0, k) * (WRK);            \
                o1 += rlf(mean1, k) * (WLK) + rlf(hv1, k) * (WRK);            \
                o2 += rlf(mean2, k) * (WLK) + rlf(hv2, k) * (WRK);            \
                o3 += rlf(mean3, k) * (WLK) + rlf(hv3, k) * (WRK);            \
            }
            DENSE_KK(wl.x, wr.x, 0)
            DENSE_KK(wl.y, wr.y, 1)
            DENSE_KK(wl.z, wr.z, 2)
            DENSE_KK(wl.w, wr.w, 3)
#undef DENSE_KK
        }

        o0 = tanhf(o0); o1 = tanhf(o1); o2 = tanhf(o2); o3 = tanhf(o3);

#define WRITE_NODE(O, N)                                                      \
        {                                                                     \
            int i = base + (N);                                               \
            if (i < n_nodes) {                                                \
                if (do_pool) {                                                \
                    atomicMaxFloat(&pooled[(size_t)batch[i] * 64 + lane], O); \
                } else {                                                      \
                    out[((size_t)i << 6) + lane] = O;                         \
                }                                                             \
            }                                                                 \
        }
        WRITE_NODE(o0, 0)
        WRITE_NODE(o1, 1)
        WRITE_NODE(o2, 2)
        WRITE_NODE(o3, 3)
#undef WRITE_NODE
    }
}

// ---------------- MLP head ----------------
__global__ void head(float* __restrict__ out, const float* __restrict__ pooled,
                     const float* __restrict__ W1, const float* __restrict__ b1,
                     const float* __restrict__ W2, const float* __restrict__ b2) {
    __shared__ float W1T[64][64];
    int tid = threadIdx.x;
    for (int t = tid; t < 4096; t += NT) {
        int f = t >> 6, k = t & 63;
        W1T[k][f] = W1[t];
    }
    __syncthreads();

    int lane = tid & 63;
    int g = blockIdx.x * (NT >> 6) + (tid >> 6);
    float v = pooled[(size_t)g * 64 + lane];
    float bias = b1[lane];
#pragma unroll
    for (int it = 0; it < 3; ++it) {
        float acc = bias;
#pragma unroll
        for (int k = 0; k < 64; ++k) {
            acc += rlf(v, k) * W1T[k][lane];
        }
        v = tanhf(acc);
    }
#pragma unroll
    for (int j = 0; j < 3; ++j) {
        float p = v * W2[j * 64 + lane];
#pragma unroll
        for (int off = 32; off >= 1; off >>= 1) p += __shfl_xor(p, off);
        if (lane == 0) out[g * 3 + j] = p + b2[j];
    }
}

// ---------------- launch ----------------

extern "C" void kernel_launch(void* const* d_in, const int* in_sizes, int n_in,
                              void* d_out, int out_size, void* d_ws, size_t ws_size,
                              hipStream_t stream) {
    const float* x   = (const float*)d_in[0];
    const float* Wl0 = (const float*)d_in[1];
    const float* Wr0 = (const float*)d_in[2];
    const float* bl0 = (const float*)d_in[3];
    const float* Wl  = (const float*)d_in[4];
    const float* Wr  = (const float*)d_in[5];
    const float* bl  = (const float*)d_in[6];
    const float* W1  = (const float*)d_in[7];
    const float* b1  = (const float*)d_in[8];
    const float* W2  = (const float*)d_in[9];
    const float* b2  = (const float*)d_in[10];
    const int* ei    = (const int*)d_in[11];
    const int* batch = (const int*)d_in[12];

    int n_nodes = in_sizes[0] / 64;
    int n_edges = in_sizes[11] / 2;
    const int* src = ei;
    const int* dst = ei + n_edges;

    int nb = (n_nodes + NT - 1) / NT;

    float* bufA   = (float*)d_ws;                         // n_nodes*64
    float* bufB   = bufA + (size_t)n_nodes * 64;          // n_nodes*64
    int* csr_src  = (int*)(bufB + (size_t)n_nodes * 64);  // n_edges
    int* row_off  = csr_src + n_edges;                    // n_nodes+1
    int* cursor   = row_off + (n_nodes + 1);              // n_nodes
    int* cnt      = cursor + n_nodes;                     // n_nodes
    int* bsum     = cnt + n_nodes;                        // nb
    int* boff     = bsum + nb;                            // nb
    float* pooled = (float*)(boff + nb);                  // 128*64

    int eblk = (n_edges + NT - 1) / NT;
    const int pers_blk = 1024;  // 4 blocks/CU x 256 CUs = 32 waves/CU

    // CSR build (parallel scan)
    zero_i32<<<nb, NT, 0, stream>>>(cnt, n_nodes);
    hist_dst<<<eblk, NT, 0, stream>>>(cnt, dst, n_edges);
    scan_blocks<<<nb, NT, 0, stream>>>(cnt, bsum, n_nodes);
    scan_bsum<<<1, 1024, 0, stream>>>(bsum, boff, nb, row_off, n_nodes);
    scan_final<<<nb, NT, 0, stream>>>(cnt, boff, row_off, cursor, n_nodes);
    edge_scatter<<<eblk, NT, 0, stream>>>(csr_src, cursor, src, dst, n_edges);

    pool_init<<<(128 * 64 + NT - 1) / NT, NT, 0, stream>>>(pooled, 128 * 64);

    sage_layer<<<pers_blk, NTS, 0, stream>>>(bufA, pooled, x, row_off, csr_src, batch,
                                             Wl0, Wr0, bl0, n_nodes, 0);
    sage_layer<<<pers_blk, NTS, 0, stream>>>(bufB, pooled, bufA, row_off, csr_src, batch,
                                             Wl, Wr, bl, n_nodes, 0);
    sage_layer<<<pers_blk, NTS, 0, stream>>>(bufA, pooled, bufB, row_off, csr_src, batch,
                                             Wl, Wr, bl, n_nodes, 0);
    sage_layer<<<pers_blk, NTS, 0, stream>>>(bufB, pooled, bufA, row_off, csr_src, batch,
                                             Wl, Wr, bl, n_nodes, 1);

    head<<<32, NT, 0, stream>>>((float*)d_out, pooled, W1, b1, W2, b2);
}

// Round 16
// 455.059 us; speedup vs baseline: 1.1179x; 1.1179x over previous
//
#include <hip/hip_runtime.h>
#include <math.h>

#define NT 256

__device__ __forceinline__ float rlf(float v, int l) {
    return __int_as_float(__builtin_amdgcn_readlane(__float_as_int(v), l));
}
__device__ __forceinline__ int rli(int v, int l) {
    return __builtin_amdgcn_readlane(v, l);
}
__device__ __forceinline__ int imax(int a, int b) { return a > b ? a : b; }

// ---------------- CSR build ----------------

__global__ void zero_i32(int* __restrict__ p, int n) {
    int t = blockIdx.x * blockDim.x + threadIdx.x;
    if (t < n) p[t] = 0;
}

__global__ void hist_dst(int* __restrict__ cnt, const int* __restrict__ dst, int n_edges) {
    int e = blockIdx.x * blockDim.x + threadIdx.x;
    if (e < n_edges) atomicAdd(&cnt[dst[e]], 1);
}

// ---- parallel 3-kernel exclusive scan of cnt[0..n) (r13-proven) ----
__global__ void scan_blocks(const int* __restrict__ cnt, int* __restrict__ bsum, int n) {
    __shared__ int s[NT];
    int i = blockIdx.x * NT + threadIdx.x;
    s[threadIdx.x] = (i < n) ? cnt[i] : 0;
    __syncthreads();
    for (int off = NT / 2; off > 0; off >>= 1) {
        if (threadIdx.x < off) s[threadIdx.x] += s[threadIdx.x + off];
        __syncthreads();
    }
    if (threadIdx.x == 0) bsum[blockIdx.x] = s[0];
}

__global__ void scan_bsum(const int* __restrict__ bsum, int* __restrict__ boff,
                          int nb, int* __restrict__ row_off, int n) {
    __shared__ int s[1024];
    int tid = threadIdx.x;
    int v = (tid < nb) ? bsum[tid] : 0;
    s[tid] = v;
    __syncthreads();
    for (int off = 1; off < 1024; off <<= 1) {
        int t = (tid >= off) ? s[tid - off] : 0;
        __syncthreads();
        s[tid] += t;
        __syncthreads();
    }
    if (tid < nb) boff[tid] = s[tid] - v;
    if (tid == nb - 1) row_off[n] = s[tid];
}

__global__ void scan_final(const int* __restrict__ cnt, const int* __restrict__ boff,
                           int* __restrict__ row_off, int* __restrict__ cursor, int n) {
    __shared__ int s[NT];
    int i = blockIdx.x * NT + threadIdx.x;
    int v = (i < n) ? cnt[i] : 0;
    s[threadIdx.x] = v;
    __syncthreads();
    for (int off = 1; off < NT; off <<= 1) {
        int t = (threadIdx.x >= off) ? s[threadIdx.x - off] : 0;
        __syncthreads();
        s[threadIdx.x] += t;
        __syncthreads();
    }
    if (i < n) {
        int ex = boff[blockIdx.x] + s[threadIdx.x] - v;
        row_off[i] = ex;
        cursor[i] = ex;
    }
}

__global__ void edge_scatter(int* __restrict__ csr_src, int* __restrict__ cursor,
                             const int* __restrict__ src, const int* __restrict__ dst,
                             int n_edges) {
    int e = blockIdx.x * blockDim.x + threadIdx.x;
    if (e < n_edges) {
        int p = atomicAdd(&cursor[dst[e]], 1);
        csr_src[p] = src[e];
    }
}

// transpose weights into [k4][f][kk] layout: out[k4*256 + f*4 + kk] = W[f*64 + k4*4 + kk]
__global__ void wtrans(float* __restrict__ out, const float* __restrict__ W) {
    int t = blockIdx.x * blockDim.x + threadIdx.x;
    if (t < 4096) {
        int kk = t & 3, f = (t >> 2) & 63, k4 = t >> 8;
        out[t] = W[f * 64 + k4 * 4 + kk];
    }
}

// ---------------- pooling helpers ----------------

__global__ void pool_init(float* __restrict__ pooled, int n) {
    int t = blockIdx.x * blockDim.x + threadIdx.x;
    if (t < n) pooled[t] = -INFINITY;
}

__device__ __forceinline__ void atomicMaxFloat(float* addr, float value) {
    if (value >= 0.0f)
        atomicMax((int*)addr, __float_as_int(value));
    else
        atomicMin((unsigned int*)addr, (unsigned int)__float_as_int(value));
}

// ---------------- fused SAGE layer (r10-proven config: 115us/layer) ----------------
// 256-thread blocks, WL in LDS (16KB -> 8 blocks/CU), WR from transposed
// global (L1-hot, hidden under dense FMAs), __launch_bounds__(256,8),
// r4 8-deep readlane gather untouched.
__global__ __launch_bounds__(NT, 8) void sage_layer(
    float* __restrict__ out, float* __restrict__ pooled,
    const float* __restrict__ h_in,
    const int* __restrict__ row_off, const int* __restrict__ csr_src,
    const int* __restrict__ batch,
    const float* __restrict__ Wl, const float* __restrict__ WrT,
    const float* __restrict__ bl,
    int n_nodes, int do_pool) {
    __shared__ float WL[4096];  // WL[k4*256 + f*4 + kk] = Wl[f][k4*4+kk]
    int tid = threadIdx.x;
    for (int t = tid; t < 4096; t += NT) {
        int kk = t & 3, f = (t >> 2) & 63, k4 = t >> 8;
        WL[t] = Wl[f * 64 + k4 * 4 + kk];
    }
    __syncthreads();

    int lane = tid & 63;
    int gwave = (blockIdx.x * NT + tid) >> 6;
    int nwaves = (gridDim.x * NT) >> 6;
    float bias = bl[lane];

    for (int q = gwave; q * 4 < n_nodes; q += nwaves) {
        int base = q * 4;
        float mean0 = 0.f, mean1 = 0.f, mean2 = 0.f, mean3 = 0.f;
        float hv0 = 0.f, hv1 = 0.f, hv2 = 0.f, hv3 = 0.f;

#define GATHER_NODE(MEAN, HV, N)                                              \
        {                                                                     \
            int i = base + (N);                                               \
            if (i < n_nodes) {                                                \
                int beg = row_off[i];                                         \
                int end_ = row_off[i + 1];                                    \
                int deg = end_ - beg;                                         \
                float a0 = 0.f, a1 = 0.f;                                     \
                for (int cb = beg; cb < end_; cb += 64) {                     \
                    int m = end_ - cb; if (m > 64) m = 64;                    \
                    int lidx = cb + (lane < m ? lane : m - 1);                \
                    int idx = csr_src[lidx];                                  \
                    for (int j = 0; j < m; j += 8) {                          \
                        int mm1 = m - 1;                                      \
                        int s0 = rli(idx, j);                                 \
                        int s1 = rli(idx, j + 1 < m ? j + 1 : mm1);           \
                        int s2 = rli(idx, j + 2 < m ? j + 2 : mm1);           \
                        int s3 = rli(idx, j + 3 < m ? j + 3 : mm1);           \
                        int s4 = rli(idx, j + 4 < m ? j + 4 : mm1);           \
                        int s5 = rli(idx, j + 5 < m ? j + 5 : mm1);           \
                        int s6 = rli(idx, j + 6 < m ? j + 6 : mm1);           \
                        int s7 = rli(idx, j + 7 < m ? j + 7 : mm1);           \
                        float v0 = h_in[s0 * 64 + lane];                      \
                        float v1 = h_in[s1 * 64 + lane];                      \
                        float v2 = h_in[s2 * 64 + lane];                      \
                        float v3 = h_in[s3 * 64 + lane];                      \
                        float v4 = h_in[s4 * 64 + lane];                      \
                        float v5 = h_in[s5 * 64 + lane];                      \
                        float v6 = h_in[s6 * 64 + lane];                      \
                        float v7 = h_in[s7 * 64 + lane];                      \
                        a0 += v0;                                             \
                        a1 += (j + 1 < m) ? v1 : 0.f;                         \
                        a0 += (j + 2 < m) ? v2 : 0.f;                         \
                        a1 += (j + 3 < m) ? v3 : 0.f;                         \
                        a0 += (j + 4 < m) ? v4 : 0.f;                         \
                        a1 += (j + 5 < m) ? v5 : 0.f;                         \
                        a0 += (j + 6 < m) ? v6 : 0.f;                         \
                        a1 += (j + 7 < m) ? v7 : 0.f;                         \
                    }                                                         \
                }                                                             \
                MEAN = (a0 + a1) * (1.0f / (float)(deg > 0 ? deg : 1));       \
                HV = h_in[(size_t)i * 64 + lane];                             \
            }                                                                 \
        }

        GATHER_NODE(mean0, hv0, 0)
        GATHER_NODE(mean1, hv1, 1)
        GATHER_NODE(mean2, hv2, 2)
        GATHER_NODE(mean3, hv3, 3)
#undef GATHER_NODE

        float o0 = bias, o1 = bias, o2 = bias, o3 = bias;
        for (int k4 = 0; k4 < 16; ++k4) {
            float4 wl = *(const float4*)&WL[k4 * 256 + lane * 4];
            float4 wr = *(const float4*)&WrT[k4 * 256 + lane * 4];
            int kb = k4 * 4;
#define DENSE_KK(WLK, WRK, KK)                                                \
            {                                                                 \
                int k = kb + (KK);                                            \
                o0 += rlf(mean0, k) * (WLK) + rlf(hv0, k) * (WRK);            \
                o1 += rlf(mean1, k) * (WLK) + rlf(hv1, k) * (WRK);            \
                o2 += rlf(mean2, k) * (WLK) + rlf(hv2, k) * (WRK);            \
                o3 += rlf(mean3, k) * (WLK) + rlf(hv3, k) * (WRK);            \
            }
            DENSE_KK(wl.x, wr.x, 0)
            DENSE_KK(wl.y, wr.y, 1)
            DENSE_KK(wl.z, wr.z, 2)
            DENSE_KK(wl.w, wr.w, 3)
#undef DENSE_KK
        }

        o0 = tanhf(o0); o1 = tanhf(o1); o2 = tanhf(o2); o3 = tanhf(o3);

#define WRITE_NODE(O, N)                                                      \
        {                                                                     \
            int i = base + (N);                                               \
            if (i < n_nodes) {                                                \
                if (do_pool) {                                                \
                    atomicMaxFloat(&pooled[(size_t)batch[i] * 64 + lane], O); \
                } else {                                                      \
                    out[(size_t)i * 64 + lane] = O;                           \
                }                                                             \
            }                                                                 \
        }
        WRITE_NODE(o0, 0)
        WRITE_NODE(o1, 1)
        WRITE_NODE(o2, 2)
        WRITE_NODE(o3, 3)
#undef WRITE_NODE
    }
}

// ---------------- MLP head ----------------
__global__ void head(float* __restrict__ out, const float* __restrict__ pooled,
                     const float* __restrict__ W1, const float* __restrict__ b1,
                     const float* __restrict__ W2, const float* __restrict__ b2) {
    __shared__ float W1T[64][64];
    int tid = threadIdx.x;
    for (int t = tid; t < 4096; t += NT) {
        int f = t >> 6, k = t & 63;
        W1T[k][f] = W1[t];
    }
    __syncthreads();

    int lane = tid & 63;
    int g = blockIdx.x * (NT >> 6) + (tid >> 6);
    float v = pooled[(size_t)g * 64 + lane];
    float bias = b1[lane];
#pragma unroll
    for (int it = 0; it < 3; ++it) {
        float acc = bias;
#pragma unroll
        for (int k = 0; k < 64; ++k) {
            acc += rlf(v, k) * W1T[k][lane];
        }
        v = tanhf(acc);
    }
#pragma unroll
    for (int j = 0; j < 3; ++j) {
        float p = v * W2[j * 64 + lane];
#pragma unroll
        for (int off = 32; off >= 1; off >>= 1) p += __shfl_xor(p, off);
        if (lane == 0) out[g * 3 + j] = p + b2[j];
    }
}

// ---------------- launch ----------------

extern "C" void kernel_launch(void* const* d_in, const int* in_sizes, int n_in,
                              void* d_out, int out_size, void* d_ws, size_t ws_size,
                              hipStream_t stream) {
    const float* x   = (const float*)d_in[0];
    const float* Wl0 = (const float*)d_in[1];
    const float* Wr0 = (const float*)d_in[2];
    const float* bl0 = (const float*)d_in[3];
    const float* Wl  = (const float*)d_in[4];
    const float* Wr  = (const float*)d_in[5];
    const float* bl  = (const float*)d_in[6];
    const float* W1  = (const float*)d_in[7];
    const float* b1  = (const float*)d_in[8];
    const float* W2  = (const float*)d_in[9];
    const float* b2  = (const float*)d_in[10];
    const int* ei    = (const int*)d_in[11];
    const int* batch = (const int*)d_in[12];

    int n_nodes = in_sizes[0] / 64;
    int n_edges = in_sizes[11] / 2;
    const int* src = ei;
    const int* dst = ei + n_edges;

    int nb = (n_nodes + NT - 1) / NT;

    float* bufA   = (float*)d_ws;                         // n_nodes*64
    float* bufB   = bufA + (size_t)n_nodes * 64;          // n_nodes*64
    int* csr_src  = (int*)(bufB + (size_t)n_nodes * 64);  // n_edges
    int* row_off  = csr_src + n_edges;                    // n_nodes+1
    int* cursor   = row_off + (n_nodes + 1);              // n_nodes
    int* cnt      = cursor + n_nodes;                     // n_nodes
    int* bsum     = cnt + n_nodes;                        // nb
    int* boff     = bsum + nb;                            // nb
    float* pooled = (float*)(boff + nb);                  // 128*64
    float* wr0t   = pooled + 128 * 64;                    // 4096
    float* wrt    = wr0t + 4096;                          // 4096

    int eblk = (n_edges + NT - 1) / NT;
    const int pers_blk = 2048;  // 8 blocks/CU x 256 CUs

    // CSR build (parallel scan, r13-proven)
    zero_i32<<<nb, NT, 0, stream>>>(cnt, n_nodes);
    hist_dst<<<eblk, NT, 0, stream>>>(cnt, dst, n_edges);
    scan_blocks<<<nb, NT, 0, stream>>>(cnt, bsum, n_nodes);
    scan_bsum<<<1, 1024, 0, stream>>>(bsum, boff, nb, row_off, n_nodes);
    scan_final<<<nb, NT, 0, stream>>>(cnt, boff, row_off, cursor, n_nodes);
    edge_scatter<<<eblk, NT, 0, stream>>>(csr_src, cursor, src, dst, n_edges);

    // transposed WR copies + pool init
    wtrans<<<16, NT, 0, stream>>>(wr0t, Wr0);
    wtrans<<<16, NT, 0, stream>>>(wrt, Wr);
    pool_init<<<(128 * 64 + NT - 1) / NT, NT, 0, stream>>>(pooled, 128 * 64);

    sage_layer<<<pers_blk, NT, 0, stream>>>(bufA, pooled, x, row_off, csr_src, batch,
                                            Wl0, wr0t, bl0, n_nodes, 0);
    sage_layer<<<pers_blk, NT, 0, stream>>>(bufB, pooled, bufA, row_off, csr_src, batch,
                                            Wl, wrt, bl, n_nodes, 0);
    sage_layer<<<pers_blk, NT, 0, stream>>>(bufA, pooled, bufB, row_off, csr_src, batch,
                                            Wl, wrt, bl, n_nodes, 0);
    sage_layer<<<pers_blk, NT, 0, stream>>>(bufB, pooled, bufA, row_off, csr_src, batch,
                                            Wl, wrt, bl, n_nodes, 1);

    head<<<32, NT, 0, stream>>>((float*)d_out, pooled, W1, b1, W2, b2);
}